// Round 1
// baseline (2067.222 us; speedup 1.0000x reference)
//
#include <hip/hip_runtime.h>
#include <hip/hip_bf16.h>

#define B_    4
#define T_    24
#define C_    4
#define H_    240
#define W_    320
#define HW_   (H_*W_)      // 76800
#define CHW_  (C_*HW_)     // 307200
#define NF_   (B_*T_)      // 96
#define NPAIR_ (B_*(T_-1)) // 92
#define PAD_  16
#define ND_   33           // shifts per axis

// ws layout (floats)
constexpr int PART_OFF = 0;                   // NF_*8*6 per-(frame,slice) partials
constexpr int MEAN_OFF = PART_OFF + NF_*8*6;  // 4608
constexpr int ISTD_OFF = MEAN_OFF + NF_;      // 4704
constexpr int Z_OFF    = ISTD_OFF + NF_;      // 4800 ; z[NPAIR_][33*33]

// ---------------------------------------------------------------------------
// Kernel 1: per-frame supervised sums + renders mean/sumsq partials.
// grid = NF_*8 blocks, 256 threads. Each block does 1/8 of one frame's pixels.
// ---------------------------------------------------------------------------
__global__ __launch_bounds__(256) void sup_stats_kernel(
    const float* __restrict__ frames, const float* __restrict__ renders,
    float* __restrict__ ws) {
  const int f = blockIdx.x >> 3;
  const int s = blockIdx.x & 7;
  const float* Fb = frames  + (size_t)f * CHW_;
  const float* Rb = renders + (size_t)f * CHW_;
  const int p0 = s * (HW_ / 8);
  const int p1 = p0 + HW_ / 8;
  float S1 = 0.f, S2 = 0.f, S3 = 0.f, MS = 0.f, SR = 0.f, SQ = 0.f;
  for (int p = p0 + (int)threadIdx.x; p < p1; p += 256) {
    float fa = Fb[3 * HW_ + p];
    float ra = Rb[3 * HW_ + p];
    float f0 = Fb[p], f1 = Fb[HW_ + p], f2 = Fb[2 * HW_ + p];
    float r0 = Rb[p], r1 = Rb[HW_ + p], r2 = Rb[2 * HW_ + p];
    float m = (fa > 0.f) ? 1.f : 0.f;
    float d = fabsf(fa - ra);
    S1 = fmaf(d, m, S1);
    S2 = fmaf(d, 1.f - m, S2);
    MS += m;
    float e = fabsf(f0 * fa - r0 * ra) + fabsf(f1 * fa - r1 * ra) +
              fabsf(f2 * fa - r2 * ra);
    S3 = fmaf(e, m, S3);
    SR += r0 + r1 + r2 + ra;
    SQ += r0 * r0 + r1 * r1 + r2 * r2 + ra * ra;
  }
  __shared__ float sm[4];
  float vals[6] = {S1, S2, S3, MS, SR, SQ};
  float* dst = ws + PART_OFF + (size_t)(f * 8 + s) * 6;
  const int wv = threadIdx.x >> 6, ln = threadIdx.x & 63;
  for (int k = 0; k < 6; ++k) {
    float v = vals[k];
    #pragma unroll
    for (int o = 32; o >= 1; o >>= 1) v += __shfl_down(v, o);
    __syncthreads();
    if (ln == 0) sm[wv] = v;
    __syncthreads();
    if (threadIdx.x == 0) dst[k] = sm[0] + sm[1] + sm[2] + sm[3];
  }
}

// ---------------------------------------------------------------------------
// Kernel 2: finalize stats -> mean/istd per frame, supervised term, out[2b].
// 1 block, 128 threads.
// ---------------------------------------------------------------------------
__global__ __launch_bounds__(128) void finalize_stats_kernel(
    float* __restrict__ ws, float* __restrict__ out) {
  __shared__ float term_s[NF_];
  const int f = threadIdx.x;
  if (f < NF_) {
    float S1 = 0, S2 = 0, S3 = 0, MS = 0, SR = 0, SQ = 0;
    for (int s = 0; s < 8; ++s) {
      const float* p = ws + PART_OFF + (size_t)(f * 8 + s) * 6;
      S1 += p[0]; S2 += p[1]; S3 += p[2]; MS += p[3]; SR += p[4]; SQ += p[5];
    }
    float mean = SR * (1.f / (float)CHW_);
    float var  = SQ * (1.f / (float)CHW_) - mean * mean;
    float sd   = sqrtf(fmaxf(var, 0.f));
    if (sd == 0.f) sd = 1.f;                 // std + (std==0)
    ws[MEAN_OFF + f] = mean;
    ws[ISTD_OFF + f] = 1.f / sd;
    float w1 = MS;               if (w1 == 0.f) w1 = 1.f;
    float w2 = (float)HW_ - MS;  if (w2 == 0.f) w2 = 1.f;
    term_s[f] = (S1 / w1 + S2 / w2 + S3 / w1) * (1.f / 3.f);
  }
  __syncthreads();
  if (threadIdx.x < B_) {
    float acc = 0.f;
    for (int t = 0; t < T_; ++t) acc += term_s[threadIdx.x * T_ + t];
    out[2 * threadIdx.x] = acc * (1.f / (float)T_);
  }
}

// ---------------------------------------------------------------------------
// Kernel 3: ZNCC correlation. One block per (pair, dy). 256 threads = 4 waves.
// Each wave owns row-pairs r = it*4+wave (c,h enumeration), stages the
// normalized a-row (with +-16 zero pad) and b-row in its private LDS region,
// then each lane accumulates acc[dx] for its 5-wide w-slice via a register
// sliding window (5 FMA per 1 ds_read_b32).
//   z[dy][dx] = (1/CHW) * sum_{c,h,w} a_n[c,h+dy,w+dx-16] * b_n[c,h,w]
// ---------------------------------------------------------------------------
__global__ __launch_bounds__(256) void zncc_kernel(
    const float* __restrict__ renders, float* __restrict__ ws) {
  const int p   = blockIdx.x / ND_;
  const int dyi = blockIdx.x - p * ND_;
  const int dy  = dyi - PAD_;
  const int bb  = p / (T_ - 1);
  const int tt  = p - bb * (T_ - 1);
  const int fa  = bb * T_ + tt;     // earlier frame = lhs (shifted operand)
  const int fb  = fa + 1;           // later frame   = kernel
  const float* A  = renders + (size_t)fa * CHW_;
  const float* Bf = renders + (size_t)fb * CHW_;
  const float ma = ws[MEAN_OFF + fa], ia = ws[ISTD_OFF + fa];
  const float mb = ws[MEAN_OFF + fb], ib = ws[ISTD_OFF + fb];
  const int Hlo = (dy < 0) ? -dy : 0;
  const int Hhi = (dy > 0) ? (H_ - dy) : H_;
  const int nh = Hhi - Hlo;
  const int total = C_ * nh;
  const int iters = (total + 3) >> 2;
  const int wv = threadIdx.x >> 6;
  const int ln = threadIdx.x & 63;

  __shared__ float a_lds[4][W_ + 2 * PAD_ + 1];  // 353 (last slide read stays in-bounds)
  __shared__ float b_lds[4][W_];
  __shared__ float zpart[4][ND_];

  float acc[ND_];
  #pragma unroll
  for (int i = 0; i < ND_; ++i) acc[i] = 0.f;

  for (int it = 0; it < iters; ++it) {
    const int r = it * 4 + wv;
    const bool act = (r < total);
    __syncthreads();                 // prior iteration's reads done before overwrite
    if (act) {
      const int c = r / nh;
      const int h = Hlo + (r - c * nh);
      const float* arow = A  + c * HW_ + (h + dy) * W_;
      const float* brow = Bf + c * HW_ + h * W_;
      for (int j = ln; j < W_ + 2 * PAD_; j += 64) {
        const int col = j - PAD_;
        float v = 0.f;
        if (col >= 0 && col < W_) v = (arow[col] - ma) * ia;
        a_lds[wv][j] = v;
      }
      for (int j = ln; j < W_; j += 64) {
        b_lds[wv][j] = (brow[j] - mb) * ib;
      }
    }
    __syncthreads();                 // staged data visible
    if (act) {
      const int base = ln * 5;       // this lane's w in [base, base+5)
      float bw0 = b_lds[wv][base + 0], bw1 = b_lds[wv][base + 1],
            bw2 = b_lds[wv][base + 2], bw3 = b_lds[wv][base + 3],
            bw4 = b_lds[wv][base + 4];
      float w0 = a_lds[wv][base + 0], w1 = a_lds[wv][base + 1],
            w2 = a_lds[wv][base + 2], w3 = a_lds[wv][base + 3],
            w4 = a_lds[wv][base + 4];
      #pragma unroll
      for (int dx = 0; dx < ND_; ++dx) {
        float sacc = w0 * bw0;
        sacc = fmaf(w1, bw1, sacc);
        sacc = fmaf(w2, bw2, sacc);
        sacc = fmaf(w3, bw3, sacc);
        sacc = fmaf(w4, bw4, sacc);
        acc[dx] += sacc;
        w0 = w1; w1 = w2; w2 = w3; w3 = w4;
        w4 = a_lds[wv][base + dx + 5];   // max idx 315+37=352 < 353
      }
    }
  }

  // reduce acc[dx] across lanes, then across waves
  #pragma unroll
  for (int dx = 0; dx < ND_; ++dx) {
    float v = acc[dx];
    #pragma unroll
    for (int o = 32; o >= 1; o >>= 1) v += __shfl_down(v, o);
    if (ln == 0) zpart[wv][dx] = v;
  }
  __syncthreads();
  if (threadIdx.x < ND_) {
    const float z = (zpart[0][threadIdx.x] + zpart[1][threadIdx.x] +
                     zpart[2][threadIdx.x] + zpart[3][threadIdx.x]) *
                    (1.f / (float)CHW_);
    ws[Z_OFF + (size_t)p * (ND_ * ND_) + dyi * ND_ + threadIdx.x] = z;
  }
}

// ---------------------------------------------------------------------------
// Kernel 4: per-pair max over 33x33, mean over t, tc -> out[2b+1].
// ---------------------------------------------------------------------------
__global__ __launch_bounds__(256) void tc_kernel(
    const float* __restrict__ ws, float* __restrict__ out) {
  const int b = blockIdx.x;
  __shared__ float sm[4];
  const int wv = threadIdx.x >> 6, ln = threadIdx.x & 63;
  float summax = 0.f;
  for (int t = 0; t < T_ - 1; ++t) {
    const float* z = ws + Z_OFF + (size_t)(b * (T_ - 1) + t) * (ND_ * ND_);
    float m = -3.4e38f;
    for (int i = threadIdx.x; i < ND_ * ND_; i += 256) m = fmaxf(m, z[i]);
    #pragma unroll
    for (int o = 32; o >= 1; o >>= 1) m = fmaxf(m, __shfl_down(m, o));
    __syncthreads();
    if (ln == 0) sm[wv] = m;
    __syncthreads();
    if (threadIdx.x == 0)
      summax += fmaxf(fmaxf(sm[0], sm[1]), fmaxf(sm[2], sm[3]));
  }
  if (threadIdx.x == 0)
    out[2 * b + 1] = (1.f - summax * (1.f / (float)(T_ - 1))) * 0.5f;
}

extern "C" void kernel_launch(void* const* d_in, const int* in_sizes, int n_in,
                              void* d_out, int out_size, void* d_ws, size_t ws_size,
                              hipStream_t stream) {
  const float* frames  = (const float*)d_in[0];
  const float* renders = (const float*)d_in[1];
  float* out = (float*)d_out;
  float* ws  = (float*)d_ws;
  hipLaunchKernelGGL(sup_stats_kernel, dim3(NF_ * 8), dim3(256), 0, stream,
                     frames, renders, ws);
  hipLaunchKernelGGL(finalize_stats_kernel, dim3(1), dim3(128), 0, stream, ws, out);
  hipLaunchKernelGGL(zncc_kernel, dim3(NPAIR_ * ND_), dim3(256), 0, stream,
                     renders, ws);
  hipLaunchKernelGGL(tc_kernel, dim3(B_), dim3(256), 0, stream, ws, out);
}

// Round 2
// 532.298 us; speedup vs baseline: 3.8836x; 3.8836x over previous
//
#include <hip/hip_runtime.h>
#include <hip/hip_bf16.h>

#define B_    4
#define T_    24
#define C_    4
#define H_    240
#define W_    320
#define HW_   (H_*W_)      // 76800
#define CHW_  (C_*HW_)     // 307200
#define NF_   (B_*T_)      // 96
#define NPAIR_ (B_*(T_-1)) // 92
#define PAD_  16
#define ND_   33           // shifts per axis
#define HC_   16           // h rows per zncc block
#define NCH_  15           // chunks (240/16)

// ws layout (floats)
constexpr int PART_OFF = 0;                   // NF_*8*6 per-(frame,slice) partials
constexpr int MEAN_OFF = PART_OFF + NF_*8*6;  // 4608
constexpr int ISTD_OFF = MEAN_OFF + NF_;      // 4704
constexpr int Z_OFF    = ISTD_OFF + NF_;      // 4800 ; z[NPAIR_][33*33]

typedef __attribute__((ext_vector_type(8))) __bf16 bf16x8;
typedef __attribute__((ext_vector_type(4))) float  f32x4;

static __device__ __forceinline__ unsigned short f2bf(float f) {
  unsigned u = __builtin_bit_cast(unsigned, f);
  unsigned r = (u + 0x7FFFu + ((u >> 16) & 1u)) >> 16;
  return (unsigned short)r;
}
static __device__ __forceinline__ unsigned pk2(float lo, float hi) {
  return (unsigned)f2bf(lo) | ((unsigned)f2bf(hi) << 16);
}

// ---------------------------------------------------------------------------
// Kernel 1: per-frame supervised sums + renders mean/sumsq partials.
// ---------------------------------------------------------------------------
__global__ __launch_bounds__(256) void sup_stats_kernel(
    const float* __restrict__ frames, const float* __restrict__ renders,
    float* __restrict__ ws) {
  const int f = blockIdx.x >> 3;
  const int s = blockIdx.x & 7;
  const float* Fb = frames  + (size_t)f * CHW_;
  const float* Rb = renders + (size_t)f * CHW_;
  const int p0 = s * (HW_ / 8);
  const int p1 = p0 + HW_ / 8;
  float S1 = 0.f, S2 = 0.f, S3 = 0.f, MS = 0.f, SR = 0.f, SQ = 0.f;
  for (int p = p0 + (int)threadIdx.x; p < p1; p += 256) {
    float fa = Fb[3 * HW_ + p];
    float ra = Rb[3 * HW_ + p];
    float f0 = Fb[p], f1 = Fb[HW_ + p], f2 = Fb[2 * HW_ + p];
    float r0 = Rb[p], r1 = Rb[HW_ + p], r2 = Rb[2 * HW_ + p];
    float m = (fa > 0.f) ? 1.f : 0.f;
    float d = fabsf(fa - ra);
    S1 = fmaf(d, m, S1);
    S2 = fmaf(d, 1.f - m, S2);
    MS += m;
    float e = fabsf(f0 * fa - r0 * ra) + fabsf(f1 * fa - r1 * ra) +
              fabsf(f2 * fa - r2 * ra);
    S3 = fmaf(e, m, S3);
    SR += r0 + r1 + r2 + ra;
    SQ += r0 * r0 + r1 * r1 + r2 * r2 + ra * ra;
  }
  __shared__ float sm[4];
  float vals[6] = {S1, S2, S3, MS, SR, SQ};
  float* dst = ws + PART_OFF + (size_t)(f * 8 + s) * 6;
  const int wv = threadIdx.x >> 6, ln = threadIdx.x & 63;
  for (int k = 0; k < 6; ++k) {
    float v = vals[k];
    #pragma unroll
    for (int o = 32; o >= 1; o >>= 1) v += __shfl_down(v, o);
    __syncthreads();
    if (ln == 0) sm[wv] = v;
    __syncthreads();
    if (threadIdx.x == 0) dst[k] = sm[0] + sm[1] + sm[2] + sm[3];
  }
}

// ---------------------------------------------------------------------------
// Kernel 2: finalize stats -> mean/istd per frame, supervised term, out[2b].
// ---------------------------------------------------------------------------
__global__ __launch_bounds__(128) void finalize_stats_kernel(
    float* __restrict__ ws, float* __restrict__ out) {
  __shared__ float term_s[NF_];
  const int f = threadIdx.x;
  if (f < NF_) {
    float S1 = 0, S2 = 0, S3 = 0, MS = 0, SR = 0, SQ = 0;
    for (int s = 0; s < 8; ++s) {
      const float* p = ws + PART_OFF + (size_t)(f * 8 + s) * 6;
      S1 += p[0]; S2 += p[1]; S3 += p[2]; MS += p[3]; SR += p[4]; SQ += p[5];
    }
    float mean = SR * (1.f / (float)CHW_);
    float var  = SQ * (1.f / (float)CHW_) - mean * mean;
    float sd   = sqrtf(fmaxf(var, 0.f));
    if (sd == 0.f) sd = 1.f;
    ws[MEAN_OFF + f] = mean;
    ws[ISTD_OFF + f] = 1.f / sd;
    float w1 = MS;               if (w1 == 0.f) w1 = 1.f;
    float w2 = (float)HW_ - MS;  if (w2 == 0.f) w2 = 1.f;
    term_s[f] = (S1 / w1 + S2 / w2 + S3 / w1) * (1.f / 3.f);
  }
  __syncthreads();
  if (threadIdx.x < B_) {
    float acc = 0.f;
    for (int t = 0; t < T_; ++t) acc += term_s[threadIdx.x * T_ + t];
    out[2 * threadIdx.x] = acc * (1.f / (float)T_);
  }
}

// ---------------------------------------------------------------------------
// Kernel 3: ZNCC via MFMA bf16.  z[dy][dx] = sum_k A[dy][k]*B[dx][k],
//   A[dyi][(c,h,w)] = a[c, h+dyi-16, w]          (h-shift; zero-pad rows)
//   B[dxi][(c,h,w)] = b[c, h, w-dxi+16]          (w-shift; zero-pad cols)
// Block = (pair, 16-row h-chunk); c-loop inside. 4 waves split the 16 rows.
// M=N=48 (3x3 tiles of 16x16x32); K per (c,row) = 320 = 10 steps of 32.
// A staged bf16, row stride 328 elems (656B: 16B-aligned, bank-balanced).
// B staged pair-packed: bs[x] = pack(b[x],b[x+1]) -> every frag dword is one
// aligned ds_read_b32 regardless of the per-lane dx shift.
// ---------------------------------------------------------------------------
__global__ __launch_bounds__(256, 2) void zncc_mfma_kernel(
    const float* __restrict__ renders, float* __restrict__ ws) {
  const int pair  = blockIdx.x / NCH_;
  const int chunk = blockIdx.x - pair * NCH_;
  const int h0 = chunk * HC_;
  const int bb = pair / (T_ - 1);
  const int tt = pair - bb * (T_ - 1);
  const int fa = bb * T_ + tt;
  const int fb = fa + 1;
  const float ma = ws[MEAN_OFF + fa], ia = ws[ISTD_OFF + fa];
  const float mb = ws[MEAN_OFF + fb], ib = ws[ISTD_OFF + fb];
  const int tid = threadIdx.x;
  const int wv = tid >> 6, ln = tid & 63;
  const int g = ln >> 4, r = ln & 15;

  __shared__ bf16x8   a_s8[64 * 41];    // 64 rows x 328 elems (41 x short8) = 41984 B
  __shared__ unsigned bs_[HC_][368];    // 16 rows x 368 pair-packed dwords  = 23552 B

  f32x4 acc[3][3];
  #pragma unroll
  for (int mi = 0; mi < 3; ++mi)
    #pragma unroll
    for (int ni = 0; ni < 3; ++ni)
      acc[mi][ni] = (f32x4){0.f, 0.f, 0.f, 0.f};

  for (int c = 0; c < C_; ++c) {
    __syncthreads();  // previous iteration's reads done before overwrite
    // ---- stage A: rows h0-16 .. h0+47 (64 rows), normalized bf16 ----
    {
      const float* Ag = renders + ((size_t)fa * C_ + c) * HW_;
      unsigned short* a_su = (unsigned short*)a_s8;
      for (int q = tid; q < 64 * 80; q += 256) {
        const int si = q / 80;
        const int c4 = (q - si * 80) << 2;
        const int gr = h0 - 16 + si;
        ushort4 s;
        if (gr >= 0 && gr < H_) {
          float4 v = *(const float4*)(Ag + (size_t)gr * W_ + c4);
          s.x = f2bf((v.x - ma) * ia);
          s.y = f2bf((v.y - ma) * ia);
          s.z = f2bf((v.z - ma) * ia);
          s.w = f2bf((v.w - ma) * ia);
        } else {
          s.x = 0; s.y = 0; s.z = 0; s.w = 0;  // pad AFTER normalize -> zeros
        }
        *(ushort4*)(a_su + si * 328 + c4) = s;
      }
    }
    // ---- stage B: rows h0..h0+15, pair-packed with 32-elem zero margins ----
    {
      const float* Bg = renders + ((size_t)fb * C_ + c) * HW_;
      for (int xq = tid; xq < HC_ * 92; xq += 256) {
        const int hr = xq / 92;
        const int x0 = (xq - hr * 92) << 2;           // dword index in row
        const float* brow = Bg + (size_t)(h0 + hr) * W_;
        float wv5[5];
        const int wbase = x0 - 32;
        #pragma unroll
        for (int k = 0; k < 5; ++k) {
          const int ww = wbase + k;
          wv5[k] = (ww >= 0 && ww < W_) ? (brow[ww] - mb) * ib : 0.f;
        }
        uint4 pk;
        pk.x = pk2(wv5[0], wv5[1]);
        pk.y = pk2(wv5[1], wv5[2]);
        pk.z = pk2(wv5[2], wv5[3]);
        pk.w = pk2(wv5[3], wv5[4]);
        *(uint4*)&bs_[hr][x0] = pk;
      }
    }
    __syncthreads();
    // ---- compute: wave wv handles rows hh = 4*ho + wv ----
    for (int ho = 0; ho < HC_ / 4; ++ho) {
      const int hh = ho * 4 + wv;
      const unsigned* bsrow = bs_[hh];
      for (int kw = 0; kw < 10; ++kw) {
        bf16x8 af[3];
        #pragma unroll
        for (int mi = 0; mi < 3; ++mi)
          af[mi] = a_s8[(hh + 16 * mi + r) * 41 + 4 * kw + g];
        bf16x8 bfr[3];
        #pragma unroll
        for (int ni = 0; ni < 3; ++ni) {
          const int pe = 32 * kw + 8 * g + 48 - 16 * ni - r;
          union { unsigned u[4]; bf16x8 v; } bu;
          bu.u[0] = bsrow[pe];
          bu.u[1] = bsrow[pe + 2];
          bu.u[2] = bsrow[pe + 4];
          bu.u[3] = bsrow[pe + 6];
          bfr[ni] = bu.v;
        }
        #pragma unroll
        for (int mi = 0; mi < 3; ++mi)
          #pragma unroll
          for (int ni = 0; ni < 3; ++ni)
            acc[mi][ni] = __builtin_amdgcn_mfma_f32_16x16x32_bf16(
                af[mi], bfr[ni], acc[mi][ni], 0, 0, 0);
      }
    }
  }

  // ---- accumulate partials into compact z[33][33] ----
  float* z = ws + Z_OFF + (size_t)pair * (ND_ * ND_);
  #pragma unroll
  for (int mi = 0; mi < 3; ++mi) {
    #pragma unroll
    for (int i = 0; i < 4; ++i) {
      const int m = 16 * mi + 4 * g + i;   // C/D: row = (lane>>4)*4 + reg
      if (m < ND_) {
        #pragma unroll
        for (int ni = 0; ni < 3; ++ni) {
          const int n = 16 * ni + r;       // C/D: col = lane&15
          if (n < ND_)
            atomicAdd(&z[m * ND_ + n], acc[mi][ni][i] * (1.f / (float)CHW_));
        }
      }
    }
  }
}

// ---------------------------------------------------------------------------
// Kernel 4: per-pair max over 33x33, mean over t, tc -> out[2b+1].
// ---------------------------------------------------------------------------
__global__ __launch_bounds__(256) void tc_kernel(
    const float* __restrict__ ws, float* __restrict__ out) {
  const int b = blockIdx.x;
  __shared__ float sm[4];
  const int wv = threadIdx.x >> 6, ln = threadIdx.x & 63;
  float summax = 0.f;
  for (int t = 0; t < T_ - 1; ++t) {
    const float* z = ws + Z_OFF + (size_t)(b * (T_ - 1) + t) * (ND_ * ND_);
    float m = -3.4e38f;
    for (int i = threadIdx.x; i < ND_ * ND_; i += 256) m = fmaxf(m, z[i]);
    #pragma unroll
    for (int o = 32; o >= 1; o >>= 1) m = fmaxf(m, __shfl_down(m, o));
    __syncthreads();
    if (ln == 0) sm[wv] = m;
    __syncthreads();
    if (threadIdx.x == 0)
      summax += fmaxf(fmaxf(sm[0], sm[1]), fmaxf(sm[2], sm[3]));
  }
  if (threadIdx.x == 0)
    out[2 * b + 1] = (1.f - summax * (1.f / (float)(T_ - 1))) * 0.5f;
}

extern "C" void kernel_launch(void* const* d_in, const int* in_sizes, int n_in,
                              void* d_out, int out_size, void* d_ws, size_t ws_size,
                              hipStream_t stream) {
  const float* frames  = (const float*)d_in[0];
  const float* renders = (const float*)d_in[1];
  float* out = (float*)d_out;
  float* ws  = (float*)d_ws;
  hipLaunchKernelGGL(sup_stats_kernel, dim3(NF_ * 8), dim3(256), 0, stream,
                     frames, renders, ws);
  hipLaunchKernelGGL(finalize_stats_kernel, dim3(1), dim3(128), 0, stream, ws, out);
  hipMemsetAsync((char*)d_ws + (size_t)Z_OFF * 4, 0,
                 (size_t)NPAIR_ * ND_ * ND_ * 4, stream);
  hipLaunchKernelGGL(zncc_mfma_kernel, dim3(NPAIR_ * NCH_), dim3(256), 0, stream,
                     renders, ws);
  hipLaunchKernelGGL(tc_kernel, dim3(B_), dim3(256), 0, stream, ws, out);
}

// Round 4
// 433.059 us; speedup vs baseline: 4.7735x; 1.2292x over previous
//
#include <hip/hip_runtime.h>
#include <hip/hip_bf16.h>

#define B_    4
#define T_    24
#define C_    4
#define H_    240
#define W_    320
#define HW_   (H_*W_)      // 76800
#define CHW_  (C_*HW_)     // 307200
#define NF_   (B_*T_)      // 96
#define NPAIR_ (B_*(T_-1)) // 92
#define PAD_  16
#define ND_   33           // shifts per axis
#define HC_   16           // h rows per zncc block
#define NCH_  15           // chunks (240/16)

// ws layout (floats)
constexpr int PART_OFF = 0;                   // NF_*8*6 per-(frame,slice) partials
constexpr int MEAN_OFF = PART_OFF + NF_*8*6;  // 4608
constexpr int ISTD_OFF = MEAN_OFF + NF_;      // 4704
constexpr int Z_OFF    = ISTD_OFF + NF_;      // 4800 ; z[NPAIR_][33*33]
constexpr int ZMAX_OFF = Z_OFF + NPAIR_*ND_*ND_;

typedef __attribute__((ext_vector_type(8))) __bf16 bf16x8;
typedef __attribute__((ext_vector_type(4))) float  f32x4;
typedef __attribute__((ext_vector_type(8))) unsigned short ushort8;

static __device__ __forceinline__ unsigned short f2bf(float f) {
  unsigned u = __builtin_bit_cast(unsigned, f);
  unsigned r = (u + 0x7FFFu + ((u >> 16) & 1u)) >> 16;
  return (unsigned short)r;
}
static __device__ __forceinline__ unsigned pk2(float lo, float hi) {
  return (unsigned)f2bf(lo) | ((unsigned)f2bf(hi) << 16);
}

// ---------------------------------------------------------------------------
// Kernel 1: per-frame supervised sums + renders mean/sumsq partials (float4).
// ---------------------------------------------------------------------------
__global__ __launch_bounds__(256) void sup_stats_kernel(
    const float* __restrict__ frames, const float* __restrict__ renders,
    float* __restrict__ ws) {
  const int f = blockIdx.x >> 3;
  const int s = blockIdx.x & 7;
  const float* Fb = frames  + (size_t)f * CHW_;
  const float* Rb = renders + (size_t)f * CHW_;
  const int p0 = s * (HW_ / 8);
  float S1 = 0.f, S2 = 0.f, S3 = 0.f, MS = 0.f, SR = 0.f, SQ = 0.f;
  for (int q = (int)threadIdx.x; q < (HW_ / 8) / 4; q += 256) {
    const int p = p0 + q * 4;
    float4 f0 = *(const float4*)(Fb + p);
    float4 f1 = *(const float4*)(Fb + HW_ + p);
    float4 f2 = *(const float4*)(Fb + 2 * HW_ + p);
    float4 fa = *(const float4*)(Fb + 3 * HW_ + p);
    float4 r0 = *(const float4*)(Rb + p);
    float4 r1 = *(const float4*)(Rb + HW_ + p);
    float4 r2 = *(const float4*)(Rb + 2 * HW_ + p);
    float4 ra = *(const float4*)(Rb + 3 * HW_ + p);
    const float F0[4] = {f0.x, f0.y, f0.z, f0.w};
    const float F1[4] = {f1.x, f1.y, f1.z, f1.w};
    const float F2[4] = {f2.x, f2.y, f2.z, f2.w};
    const float FA[4] = {fa.x, fa.y, fa.z, fa.w};
    const float R0[4] = {r0.x, r0.y, r0.z, r0.w};
    const float R1[4] = {r1.x, r1.y, r1.z, r1.w};
    const float R2[4] = {r2.x, r2.y, r2.z, r2.w};
    const float RA[4] = {ra.x, ra.y, ra.z, ra.w};
    #pragma unroll
    for (int k = 0; k < 4; ++k) {
      float m = (FA[k] > 0.f) ? 1.f : 0.f;
      float d = fabsf(FA[k] - RA[k]);
      S1 = fmaf(d, m, S1);
      S2 = fmaf(d, 1.f - m, S2);
      MS += m;
      float e = fabsf(F0[k] * FA[k] - R0[k] * RA[k]) +
                fabsf(F1[k] * FA[k] - R1[k] * RA[k]) +
                fabsf(F2[k] * FA[k] - R2[k] * RA[k]);
      S3 = fmaf(e, m, S3);
      SR += R0[k] + R1[k] + R2[k] + RA[k];
      SQ += R0[k] * R0[k] + R1[k] * R1[k] + R2[k] * R2[k] + RA[k] * RA[k];
    }
  }
  __shared__ float sm[4];
  float vals[6] = {S1, S2, S3, MS, SR, SQ};
  float* dst = ws + PART_OFF + (size_t)(f * 8 + s) * 6;
  const int wv = threadIdx.x >> 6, ln = threadIdx.x & 63;
  for (int k = 0; k < 6; ++k) {
    float v = vals[k];
    #pragma unroll
    for (int o = 32; o >= 1; o >>= 1) v += __shfl_down(v, o);
    __syncthreads();
    if (ln == 0) sm[wv] = v;
    __syncthreads();
    if (threadIdx.x == 0) dst[k] = sm[0] + sm[1] + sm[2] + sm[3];
  }
}

// ---------------------------------------------------------------------------
// Kernel 2: finalize stats -> mean/istd per frame, supervised term, out[2b].
// ---------------------------------------------------------------------------
__global__ __launch_bounds__(128) void finalize_stats_kernel(
    float* __restrict__ ws, float* __restrict__ out) {
  __shared__ float term_s[NF_];
  const int f = threadIdx.x;
  if (f < NF_) {
    float S1 = 0, S2 = 0, S3 = 0, MS = 0, SR = 0, SQ = 0;
    for (int s = 0; s < 8; ++s) {
      const float* p = ws + PART_OFF + (size_t)(f * 8 + s) * 6;
      S1 += p[0]; S2 += p[1]; S3 += p[2]; MS += p[3]; SR += p[4]; SQ += p[5];
    }
    float mean = SR * (1.f / (float)CHW_);
    float var  = SQ * (1.f / (float)CHW_) - mean * mean;
    float sd   = sqrtf(fmaxf(var, 0.f));
    if (sd == 0.f) sd = 1.f;
    ws[MEAN_OFF + f] = mean;
    ws[ISTD_OFF + f] = 1.f / sd;
    float w1 = MS;               if (w1 == 0.f) w1 = 1.f;
    float w2 = (float)HW_ - MS;  if (w2 == 0.f) w2 = 1.f;
    term_s[f] = (S1 / w1 + S2 / w2 + S3 / w1) * (1.f / 3.f);
  }
  __syncthreads();
  if (threadIdx.x < B_) {
    float acc = 0.f;
    for (int t = 0; t < T_; ++t) acc += term_s[threadIdx.x * T_ + t];
    out[2 * threadIdx.x] = acc * (1.f / (float)T_);
  }
}

// ---------------------------------------------------------------------------
// Kernel 3: ZNCC via MFMA bf16, 512 threads (8 waves), kw fully unrolled so
// all LDS reads are base+imm-offset (A: 3 bases b128; B: 3 bases, stride-2
// dword pairs -> ds_read2_b32 mergeable).
// ---------------------------------------------------------------------------
__global__ __launch_bounds__(512, 4) void zncc_mfma_kernel(
    const float* __restrict__ renders, float* __restrict__ ws) {
  const int pair  = blockIdx.x / NCH_;
  const int chunk = blockIdx.x - pair * NCH_;
  const int h0 = chunk * HC_;
  const int bb = pair / (T_ - 1);
  const int tt = pair - bb * (T_ - 1);
  const int fa = bb * T_ + tt;
  const int fb = fa + 1;
  const float ma = ws[MEAN_OFF + fa], ia = ws[ISTD_OFF + fa];
  const float mb = ws[MEAN_OFF + fb], ib = ws[ISTD_OFF + fb];
  const int tid = threadIdx.x;
  const int wv = tid >> 6, ln = tid & 63;
  const int g = ln >> 4, r = ln & 15;

  __shared__ alignas(16) unsigned short a_su[64 * 328];  // 41984 B
  __shared__ alignas(16) unsigned bs_[HC_][368];         // 23552 B  (total 64 KB)

  f32x4 acc[3][3];
  #pragma unroll
  for (int mi = 0; mi < 3; ++mi)
    #pragma unroll
    for (int ni = 0; ni < 3; ++ni)
      acc[mi][ni] = (f32x4){0.f, 0.f, 0.f, 0.f};

  for (int c = 0; c < C_; ++c) {
    __syncthreads();  // prior compute reads done before overwrite
    // ---- stage A: 64 rows (h0-16..h0+47), normalized bf16, ushort8 writes ----
    {
      const float* Ag = renders + ((size_t)fa * C_ + c) * HW_;
      for (int q = tid; q < 64 * 40; q += 512) {
        const int si = q / 40;
        const int j8 = (q - si * 40) << 3;
        const int gr = h0 - 16 + si;
        ushort8 sv = (ushort8)0;
        if (gr >= 0 && gr < H_) {
          const float* src = Ag + (size_t)gr * W_ + j8;
          float4 v0 = *(const float4*)(src);
          float4 v1 = *(const float4*)(src + 4);
          sv[0] = f2bf((v0.x - ma) * ia); sv[1] = f2bf((v0.y - ma) * ia);
          sv[2] = f2bf((v0.z - ma) * ia); sv[3] = f2bf((v0.w - ma) * ia);
          sv[4] = f2bf((v1.x - ma) * ia); sv[5] = f2bf((v1.y - ma) * ia);
          sv[6] = f2bf((v1.z - ma) * ia); sv[7] = f2bf((v1.w - ma) * ia);
        }
        *(ushort8*)(a_su + si * 328 + j8) = sv;
      }
    }
    // ---- stage B: 16 rows, pair-packed with 32-elem zero margins ----
    {
      const float* Bg = renders + ((size_t)fb * C_ + c) * HW_;
      for (int xq = tid; xq < HC_ * 92; xq += 512) {
        const int hr = xq / 92;
        const int x0 = (xq - hr * 92) << 2;
        const float* brow = Bg + (size_t)(h0 + hr) * W_;
        float wv5[5];
        const int wbase = x0 - 32;
        #pragma unroll
        for (int k = 0; k < 5; ++k) {
          const int ww = wbase + k;
          wv5[k] = (ww >= 0 && ww < W_) ? (brow[ww] - mb) * ib : 0.f;
        }
        uint4 pk;
        pk.x = pk2(wv5[0], wv5[1]);
        pk.y = pk2(wv5[1], wv5[2]);
        pk.z = pk2(wv5[2], wv5[3]);
        pk.w = pk2(wv5[3], wv5[4]);
        *(uint4*)&bs_[hr][x0] = pk;
      }
    }
    __syncthreads();
    // ---- compute: wave wv handles rows hh = ho*8 + wv ----
    for (int ho = 0; ho < 2; ++ho) {
      const int hh = ho * 8 + wv;
      const unsigned* bsrow = &bs_[hh][0];
      const unsigned short* arow = a_su + (hh + r) * 328 + g * 8;
      #pragma unroll
      for (int kw = 0; kw < 10; ++kw) {
        bf16x8 af[3];
        #pragma unroll
        for (int mi = 0; mi < 3; ++mi)
          af[mi] = *(const bf16x8*)(arow + mi * (16 * 328) + kw * 32);
        bf16x8 bfr[3];
        #pragma unroll
        for (int ni = 0; ni < 3; ++ni) {
          const int pe = 32 * kw + 8 * g + 48 - 16 * ni - r;
          union { unsigned u[4]; bf16x8 v; } bu;
          bu.u[0] = bsrow[pe];
          bu.u[1] = bsrow[pe + 2];
          bu.u[2] = bsrow[pe + 4];
          bu.u[3] = bsrow[pe + 6];
          bfr[ni] = bu.v;
        }
        #pragma unroll
        for (int mi = 0; mi < 3; ++mi)
          #pragma unroll
          for (int ni = 0; ni < 3; ++ni)
            acc[mi][ni] = __builtin_amdgcn_mfma_f32_16x16x32_bf16(
                af[mi], bfr[ni], acc[mi][ni], 0, 0, 0);
      }
    }
  }

  // ---- cross-wave pair reduction in LDS (aliased over a_su), then atomics ----
  __syncthreads();
  f32x4* red = (f32x4*)a_su;   // need 4*64*9*16B = 36864 B <= 41984 B
  if (wv >= 4) {
    f32x4* dst = red + ((wv - 4) * 64 + ln) * 9;
    #pragma unroll
    for (int mi = 0; mi < 3; ++mi)
      #pragma unroll
      for (int ni = 0; ni < 3; ++ni)
        dst[mi * 3 + ni] = acc[mi][ni];
  }
  __syncthreads();
  if (wv < 4) {
    const f32x4* src = red + (wv * 64 + ln) * 9;
    #pragma unroll
    for (int mi = 0; mi < 3; ++mi)
      #pragma unroll
      for (int ni = 0; ni < 3; ++ni)
        acc[mi][ni] += src[mi * 3 + ni];
    float* z = ws + Z_OFF + (size_t)pair * (ND_ * ND_);
    #pragma unroll
    for (int mi = 0; mi < 3; ++mi) {
      #pragma unroll
      for (int i = 0; i < 4; ++i) {
        const int m = 16 * mi + 4 * g + i;   // C/D: row = (lane>>4)*4 + reg
        if (m < ND_) {
          #pragma unroll
          for (int ni = 0; ni < 3; ++ni) {
            const int n = 16 * ni + r;       // C/D: col = lane&15
            if (n < ND_)
              atomicAdd(&z[m * ND_ + n], acc[mi][ni][i] * (1.f / (float)CHW_));
          }
        }
      }
    }
  }
}

// ---------------------------------------------------------------------------
// Kernel 4a: per-pair max over 33x33 -> ws[ZMAX_OFF+pair]. 92 blocks.
// ---------------------------------------------------------------------------
__global__ __launch_bounds__(256) void tc_max_kernel(
    const float* __restrict__ ws, float* __restrict__ wso) {
  const int pair = blockIdx.x;
  const float* z = ws + Z_OFF + (size_t)pair * (ND_ * ND_);
  float m = -3.4e38f;
  for (int i = threadIdx.x; i < ND_ * ND_; i += 256) m = fmaxf(m, z[i]);
  #pragma unroll
  for (int o = 32; o >= 1; o >>= 1) m = fmaxf(m, __shfl_down(m, o));
  __shared__ float sm[4];
  const int wv = threadIdx.x >> 6, ln = threadIdx.x & 63;
  if (ln == 0) sm[wv] = m;
  __syncthreads();
  if (threadIdx.x == 0)
    wso[ZMAX_OFF + pair] = fmaxf(fmaxf(sm[0], sm[1]), fmaxf(sm[2], sm[3]));
}

// ---------------------------------------------------------------------------
// Kernel 4b: tc final: out[2b+1]. 1 block.
// ---------------------------------------------------------------------------
__global__ __launch_bounds__(128) void tc_final_kernel(
    const float* __restrict__ ws, float* __restrict__ out) {
  if (threadIdx.x < B_) {
    float s = 0.f;
    for (int t = 0; t < T_ - 1; ++t)
      s += ws[ZMAX_OFF + threadIdx.x * (T_ - 1) + t];
    out[2 * threadIdx.x + 1] = (1.f - s * (1.f / (float)(T_ - 1))) * 0.5f;
  }
}

extern "C" void kernel_launch(void* const* d_in, const int* in_sizes, int n_in,
                              void* d_out, int out_size, void* d_ws, size_t ws_size,
                              hipStream_t stream) {
  const float* frames  = (const float*)d_in[0];
  const float* renders = (const float*)d_in[1];
  float* out = (float*)d_out;
  float* ws  = (float*)d_ws;
  hipLaunchKernelGGL(sup_stats_kernel, dim3(NF_ * 8), dim3(256), 0, stream,
                     frames, renders, ws);
  hipLaunchKernelGGL(finalize_stats_kernel, dim3(1), dim3(128), 0, stream, ws, out);
  hipMemsetAsync((char*)d_ws + (size_t)Z_OFF * 4, 0,
                 (size_t)NPAIR_ * ND_ * ND_ * 4, stream);
  hipLaunchKernelGGL(zncc_mfma_kernel, dim3(NPAIR_ * NCH_), dim3(512), 0, stream,
                     renders, ws);
  hipLaunchKernelGGL(tc_max_kernel, dim3(NPAIR_), dim3(256), 0, stream, ws, ws);
  hipLaunchKernelGGL(tc_final_kernel, dim3(1), dim3(128), 0, stream, ws, out);
}